// Round 9
// baseline (647.080 us; speedup 1.0000x reference)
//
#include <hip/hip_runtime.h>
#include <hip/hip_bf16.h>

// Problem constants
#define BB 8
#define NN 100
#define DIMM 256
#define HEADSS 8
#define HDD 32
#define FFNN 2048
#define MM 16384               // H*W = 128*128
#define ROWS (BB*NN)           // 800
#define CTX_ROWS (BB*MM)       // 131072
#define SCALE 0.17677669529663689f   // 1/sqrt(32)

typedef __attribute__((ext_vector_type(8))) short s16x8;
typedef __attribute__((ext_vector_type(4))) float f32x4;

__device__ inline ushort f2bf(float f) {
    union { float f; unsigned u; } c; c.f = f;
    unsigned r = c.u + 0x7fffu + ((c.u >> 16) & 1u);
    return (ushort)(r >> 16);
}
__device__ inline float bf2f(ushort u) {
    union { unsigned i; float f; } c; c.i = ((unsigned)u) << 16; return c.f;
}

// ---------------- fp32 -> bf16 bulk convert (for weights) ----------------
__global__ __launch_bounds__(256) void conv_bf16(const float* __restrict__ src,
                                                 ushort* __restrict__ dst, int n4) {
    int i = blockIdx.x * 256 + threadIdx.x;
    if (i < n4) {
        float4 v = ((const float4*)src)[i];
        union { ushort u[4]; uint2 v2; } o;
        o.u[0] = f2bf(v.x); o.u[1] = f2bf(v.y); o.u[2] = f2bf(v.z); o.u[3] = f2bf(v.w);
        *(uint2*)&dst[i * 4] = o.v2;
    }
}

// ---------------- LayerNorm (dim=256), one block per row ----------------
__global__ void ln_kernel(const float* __restrict__ x, const float* __restrict__ g,
                          const float* __restrict__ beta, float* __restrict__ y) {
    int row = blockIdx.x;
    int t = threadIdx.x;
    float v = x[row * 256 + t];
    __shared__ float red[256];
    red[t] = v; __syncthreads();
    for (int s = 128; s > 0; s >>= 1) { if (t < s) red[t] += red[t + s]; __syncthreads(); }
    float mu = red[0] * (1.0f / 256.0f);
    __syncthreads();
    float d = v - mu;
    red[t] = d * d; __syncthreads();
    for (int s = 128; s > 0; s >>= 1) { if (t < s) red[t] += red[t + s]; __syncthreads(); }
    float var = red[0] * (1.0f / 256.0f);
    float r = rsqrtf(var + 1e-5f);
    y[row * 256 + t] = d * r * g[t] + beta[t];
}

// ---------------- MFMA projection GEMM: out[M][C] = act(A[M][K] @ W[C][K]^T + bias) (+res)
// BM=64, BN=64, BK=64; 4 waves (2x2), each wave 32x32 = 2x2 fragments of 16x16x32.
// LDS layout [row][64] with XOR granule swizzle (granule ^= row&7) -> conflict-free.
template<bool GELU, bool RES>
__global__ __launch_bounds__(256) void gemm_proj(const float* __restrict__ A,
                                                 const float* __restrict__ W,
                                                 const float* __restrict__ bias,
                                                 const float* __restrict__ res,
                                                 float* __restrict__ out,
                                                 int M, int K, int C) {
    int bm = blockIdx.x, bn = blockIdx.y;
    __shared__ __align__(16) ushort As[64 * 64];
    __shared__ __align__(16) ushort Bs[64 * 64];
    int t = threadIdx.x;
    int lane = t & 63, w = t >> 6;
    int wr = w >> 1, wc = w & 1;
    int l15 = lane & 15, lk = lane >> 4;
    int l7 = l15 & 7;

    f32x4 acc[2][2];
    #pragma unroll
    for (int i = 0; i < 2; i++)
        #pragma unroll
        for (int j = 0; j < 2; j++)
            acc[i][j] = (f32x4){0.f, 0.f, 0.f, 0.f};

    int srow = t >> 2;            // 0..63
    int sg0 = (t & 3) * 2;        // granule pair base: 0,2,4,6
    int swz0 = (sg0 ^ (srow & 7)) * 8;
    int swz1 = ((sg0 + 1) ^ (srow & 7)) * 8;
    int scol = sg0 * 8;           // global k offset 0,16,32,48

    int nkt = K >> 6;
    for (int kt = 0; kt < nkt; ++kt) {
        int kb = kt * 64 + scol;
        // stage A (row-guarded) and B
        {
            int gr = bm * 64 + srow;
            s16x8 va0 = {0,0,0,0,0,0,0,0}, va1 = {0,0,0,0,0,0,0,0};
            if (gr < M) {
                const float* ap = A + (size_t)gr * K + kb;
                float4 a0 = *(const float4*)ap;
                float4 a1 = *(const float4*)(ap + 4);
                float4 a2 = *(const float4*)(ap + 8);
                float4 a3 = *(const float4*)(ap + 12);
                va0[0] = (short)f2bf(a0.x); va0[1] = (short)f2bf(a0.y);
                va0[2] = (short)f2bf(a0.z); va0[3] = (short)f2bf(a0.w);
                va0[4] = (short)f2bf(a1.x); va0[5] = (short)f2bf(a1.y);
                va0[6] = (short)f2bf(a1.z); va0[7] = (short)f2bf(a1.w);
                va1[0] = (short)f2bf(a2.x); va1[1] = (short)f2bf(a2.y);
                va1[2] = (short)f2bf(a2.z); va1[3] = (short)f2bf(a2.w);
                va1[4] = (short)f2bf(a3.x); va1[5] = (short)f2bf(a3.y);
                va1[6] = (short)f2bf(a3.z); va1[7] = (short)f2bf(a3.w);
            }
            *(s16x8*)&As[srow * 64 + swz0] = va0;
            *(s16x8*)&As[srow * 64 + swz1] = va1;
            const float* bp = W + (size_t)(bn * 64 + srow) * K + kb;
            float4 b0 = *(const float4*)bp;
            float4 b1 = *(const float4*)(bp + 4);
            float4 b2 = *(const float4*)(bp + 8);
            float4 b3 = *(const float4*)(bp + 12);
            s16x8 vb0, vb1;
            vb0[0] = (short)f2bf(b0.x); vb0[1] = (short)f2bf(b0.y);
            vb0[2] = (short)f2bf(b0.z); vb0[3] = (short)f2bf(b0.w);
            vb0[4] = (short)f2bf(b1.x); vb0[5] = (short)f2bf(b1.y);
            vb0[6] = (short)f2bf(b1.z); vb0[7] = (short)f2bf(b1.w);
            vb1[0] = (short)f2bf(b2.x); vb1[1] = (short)f2bf(b2.y);
            vb1[2] = (short)f2bf(b2.z); vb1[3] = (short)f2bf(b2.w);
            vb1[4] = (short)f2bf(b3.x); vb1[5] = (short)f2bf(b3.y);
            vb1[6] = (short)f2bf(b3.z); vb1[7] = (short)f2bf(b3.w);
            *(s16x8*)&Bs[srow * 64 + swz0] = vb0;
            *(s16x8*)&Bs[srow * 64 + swz1] = vb1;
        }
        __syncthreads();
        #pragma unroll
        for (int kk = 0; kk < 64; kk += 32) {
            int gsw = (((kk >> 3) + lk) ^ l7) * 8;    // fragment row&7 == l15&7
            s16x8 af[2], bf[2];
            #pragma unroll
            for (int mi = 0; mi < 2; mi++)
                af[mi] = *(const s16x8*)&As[(wr * 32 + mi * 16 + l15) * 64 + gsw];
            #pragma unroll
            for (int ni = 0; ni < 2; ni++)
                bf[ni] = *(const s16x8*)&Bs[(wc * 32 + ni * 16 + l15) * 64 + gsw];
            #pragma unroll
            for (int mi = 0; mi < 2; mi++)
                #pragma unroll
                for (int ni = 0; ni < 2; ni++)
                    acc[mi][ni] = __builtin_amdgcn_mfma_f32_16x16x32_bf16(af[mi], bf[ni], acc[mi][ni], 0, 0, 0);
        }
        __syncthreads();
    }
    // epilogue
    #pragma unroll
    for (int ni = 0; ni < 2; ni++) {
        int col = bn * 64 + wc * 32 + ni * 16 + l15;
        float bv = bias[col];
        #pragma unroll
        for (int mi = 0; mi < 2; mi++) {
            int row0 = bm * 64 + wr * 32 + mi * 16 + lk * 4;
            #pragma unroll
            for (int r = 0; r < 4; r++) {
                int gr = row0 + r;
                if (gr < M) {
                    float v = acc[mi][ni][r] + bv;
                    if (GELU) v = 0.5f * v * (1.0f + erff(v * 0.70710678118654752f));
                    if (RES)  v += res[(size_t)gr * C + col];
                    out[(size_t)gr * C + col] = v;
                }
            }
        }
    }
}

// ---------------- KV projection as bf16 MFMA GEMM, head-major K/V output ------------
// Kh/Vh[(b*8+h)][m][32] bf16.  Linear grid 4096 with XCD-grouping swizzle:
// bm=(i>>5)*8+(i&7), bn=(i>>3)&3 -> the 4 bn-sharers of an A-tile have the same i%8
// (same XCD under round-robin) -> A fetched ~once into that XCD's L2.
// B pre-converted to bf16 (Wbf). 2-phase register prefetch hides HBM latency.
__global__ __launch_bounds__(256) void gemm_kv(const float* __restrict__ A,
                                               const ushort* __restrict__ Wbf,
                                               const float* __restrict__ bias,
                                               ushort* __restrict__ Kh,
                                               ushort* __restrict__ Vh) {
    int i = blockIdx.x;
    int bm = ((i >> 5) << 3) + (i & 7);   // 0..1023
    int bn = (i >> 3) & 3;                // 0..3
    __shared__ __align__(16) ushort As[128 * 64];   // 16 KB
    __shared__ __align__(16) ushort Bs[128 * 64];   // 16 KB
    int t = threadIdx.x;
    int lane = t & 63;
    int w = t >> 6;
    int wr = w >> 1, wc = w & 1;
    int l15 = lane & 15, lk = lane >> 4;
    int l7 = l15 & 7;

    f32x4 acc[4][4];
    #pragma unroll
    for (int ii = 0; ii < 4; ii++)
        #pragma unroll
        for (int j = 0; j < 4; j++)
            acc[ii][j] = (f32x4){0.f, 0.f, 0.f, 0.f};

    int srow = t >> 3;          // 0..31
    int sg   = t & 7;           // granule 0..7
    int skk  = sg * 8;          // k offset within 64
    int swz  = (sg ^ (srow & 7)) * 8;

    const float*  Abase = A   + (size_t)(bm * 128) * 256;
    const ushort* Bbase = Wbf + (size_t)(bn * 128) * 256;

    float4 ra[4][2];
    uint4  rb[4];

    // prologue: issue kt=0 loads
    {
        int kbase = 0;
        #pragma unroll
        for (int p = 0; p < 4; p++) {
            int row = p * 32 + srow;
            const float* ap = Abase + (size_t)row * 256 + kbase + skk;
            ra[p][0] = *(const float4*)ap;
            ra[p][1] = *(const float4*)(ap + 4);
            rb[p] = *(const uint4*)(Bbase + (size_t)row * 256 + kbase + skk);
        }
    }

    for (int kt = 0; kt < 4; ++kt) {
        // convert + stage current kt
        #pragma unroll
        for (int p = 0; p < 4; p++) {
            int row = p * 32 + srow;
            s16x8 va;
            va[0] = (short)f2bf(ra[p][0].x); va[1] = (short)f2bf(ra[p][0].y);
            va[2] = (short)f2bf(ra[p][0].z); va[3] = (short)f2bf(ra[p][0].w);
            va[4] = (short)f2bf(ra[p][1].x); va[5] = (short)f2bf(ra[p][1].y);
            va[6] = (short)f2bf(ra[p][1].z); va[7] = (short)f2bf(ra[p][1].w);
            *(s16x8*)&As[row * 64 + swz] = va;
            *(uint4*)&Bs[row * 64 + swz] = rb[p];
        }
        __syncthreads();
        // issue kt+1 loads (in flight during MFMA below)
        if (kt < 3) {
            int kbase = (kt + 1) * 64;
            #pragma unroll
            for (int p = 0; p < 4; p++) {
                int row = p * 32 + srow;
                const float* ap = Abase + (size_t)row * 256 + kbase + skk;
                ra[p][0] = *(const float4*)ap;
                ra[p][1] = *(const float4*)(ap + 4);
                rb[p] = *(const uint4*)(Bbase + (size_t)row * 256 + kbase + skk);
            }
        }
        #pragma unroll
        for (int kk = 0; kk < 64; kk += 32) {
            int gsw = (((kk >> 3) + lk) ^ l7) * 8;
            s16x8 af[4], bf[4];
            #pragma unroll
            for (int mi = 0; mi < 4; mi++)
                af[mi] = *(const s16x8*)&As[(wr * 64 + mi * 16 + l15) * 64 + gsw];
            #pragma unroll
            for (int ni = 0; ni < 4; ni++)
                bf[ni] = *(const s16x8*)&Bs[(wc * 64 + ni * 16 + l15) * 64 + gsw];
            #pragma unroll
            for (int mi = 0; mi < 4; mi++)
                #pragma unroll
                for (int ni = 0; ni < 4; ni++)
                    acc[mi][ni] = __builtin_amdgcn_mfma_f32_16x16x32_bf16(af[mi], bf[ni], acc[mi][ni], 0, 0, 0);
        }
        __syncthreads();
    }
    // epilogue: bias add + bf16 store, head-major K/V split
    #pragma unroll
    for (int ni = 0; ni < 4; ni++) {
        int col = bn * 128 + wc * 64 + ni * 16 + l15;
        float bv = bias[col];
        int isV = col >> 8;              // 0: K, 1: V
        int c2 = col & 255;
        int h = c2 >> 5, hd = c2 & 31;
        ushort* dst = isV ? Vh : Kh;
        #pragma unroll
        for (int mi = 0; mi < 4; mi++) {
            int row0 = bm * 128 + wr * 64 + mi * 16 + lk * 4;
            #pragma unroll
            for (int r = 0; r < 4; r++) {
                int gr = row0 + r;
                int b = gr >> 14, m = gr & 16383;
                dst[(((size_t)(b * 8 + h)) * 16384 + m) * 32 + hd] = f2bf(acc[mi][ni][r] + bv);
            }
        }
    }
}

// ---------------- Mask bit-pack: Mb[b][n(128 padded)][512] uint32 --------------------
__global__ __launch_bounds__(256) void pack_mask(const int* __restrict__ mask,
                                                 unsigned* __restrict__ Mb) {
    unsigned tid = blockIdx.x * 256 + threadIdx.x;   // up to 2^24
    int b = tid >> 21;
    int rem = tid & ((1u << 21) - 1);
    int n = rem >> 14;
    int m = rem & 16383;
    int mv = 0;
    if (n < 100) mv = mask[(((size_t)b * 100 + n) << 14) + m];
    unsigned long long bal = __ballot(mv != 0);
    if ((threadIdx.x & 63) == 0) {
        size_t widx = (((size_t)b * 128 + n) << 9) + (m >> 5);   // even
        *(unsigned long long*)(Mb + widx) = bal;
    }
}

// ---------------- Flash masked cross-attention (MFMA) -------------------------------
// grid (chunk=8, h=8, b=8), 256 threads (4 waves x 32 q-rows). Each chunk = 2048 kv.
__global__ __launch_bounds__(256) void xattn_flash(
        const float* __restrict__ q,          // [b][100][256]
        const ushort* __restrict__ Kh,        // [(b*8+h)][16384][32]
        const ushort* __restrict__ Vh,
        const unsigned* __restrict__ Mb,      // [b][128][512]
        float* __restrict__ O_part,           // [(b*8+h)*8+ch][128][32]
        float* __restrict__ m_part,           // [(b*8+h)*8+ch][128]
        float* __restrict__ l_part) {
    int ch = blockIdx.x;
    int h = blockIdx.y, b = blockIdx.z;
    int t = threadIdx.x;
    int lane = t & 63, w = t >> 6;
    int l15 = lane & 15, g = lane >> 4;

    __shared__ __align__(16) ushort Qs[128 * 40];   // 10240 B
    __shared__ __align__(16) ushort Ks[64 * 40];    // 5120 B
    __shared__ __align__(16) ushort Vt[32 * 72];    // 4608 B  (V transposed: [d][kv])
    __shared__ __align__(16) ushort Ps[128 * 72];   // 18432 B
    __shared__ unsigned Ms[128 * 64];               // 32768 B

    // ---- stage Q (scaled, bf16, zero-pad rows >= 100) ----
    {
        int r = t >> 1, dh = (t & 1) * 16;
        s16x8 v0 = {0,0,0,0,0,0,0,0}, v1 = {0,0,0,0,0,0,0,0};
        if (r < 100) {
            const float* qp = q + ((size_t)(b * 100 + r)) * 256 + h * 32 + dh;
            #pragma unroll
            for (int j = 0; j < 8; j++) v0[j] = (short)f2bf(qp[j] * SCALE);
            #pragma unroll
            for (int j = 0; j < 8; j++) v1[j] = (short)f2bf(qp[8 + j] * SCALE);
        }
        *(s16x8*)&Qs[r * 40 + dh] = v0;
        *(s16x8*)&Qs[r * 40 + dh + 8] = v1;
    }
    // ---- stage mask chunk: Ms[q][64 words] ----
    {
        const unsigned* mp = Mb + (((size_t)b * 128) << 9) + ch * 64;
        #pragma unroll
        for (int i = 0; i < 32; i++) {
            int idx = t + i * 256;
            int r = idx >> 6, wd = idx & 63;
            Ms[idx] = mp[((size_t)r << 9) + wd];
        }
    }
    __syncthreads();

    // Q fragments (persist in registers)
    s16x8 aq[2];
    aq[0] = *(const s16x8*)&Qs[(w * 32 + l15) * 40 + g * 8];
    aq[1] = *(const s16x8*)&Qs[(w * 32 + 16 + l15) * 40 + g * 8];

    float m_run[2][4], l_run[2][4];
    f32x4 accO[2][2];
    #pragma unroll
    for (int qt = 0; qt < 2; qt++) {
        #pragma unroll
        for (int r = 0; r < 4; r++) { m_run[qt][r] = -1e30f; l_run[qt][r] = 0.f; }
        accO[qt][0] = (f32x4){0.f,0.f,0.f,0.f};
        accO[qt][1] = (f32x4){0.f,0.f,0.f,0.f};
    }

    const ushort* Kbase = Kh + (((size_t)(b * 8 + h)) * 16384 + (size_t)ch * 2048) * 32;
    const ushort* Vbase = Vh + (((size_t)(b * 8 + h)) * 16384 + (size_t)ch * 2048) * 32;

    for (int tile = 0; tile < 32; ++tile) {
        if (tile) __syncthreads();
        // ---- stage K[64][40] and V transposed [32][72] ----
        {
            int mrow = t >> 2, d0 = (t & 3) * 8;
            uint4 k4 = *(const uint4*)(Kbase + ((size_t)(tile * 64 + mrow)) * 32 + d0);
            *(uint4*)&Ks[mrow * 40 + d0] = k4;
            uint4 v4 = *(const uint4*)(Vbase + ((size_t)(tile * 64 + mrow)) * 32 + d0);
            const ushort* vsp = (const ushort*)&v4;
            #pragma unroll
            for (int j = 0; j < 8; j++) Vt[(d0 + j) * 72 + mrow] = vsp[j];
        }
        __syncthreads();

        // ---- QK^T: S[q 32][kv 64] per wave ----
        s16x8 bk[4];
        #pragma unroll
        for (int ni = 0; ni < 4; ni++)
            bk[ni] = *(const s16x8*)&Ks[(ni * 16 + l15) * 40 + g * 8];
        f32x4 sfrag[2][4];
        #pragma unroll
        for (int qt = 0; qt < 2; qt++)
            #pragma unroll
            for (int ni = 0; ni < 4; ni++)
                sfrag[qt][ni] = __builtin_amdgcn_mfma_f32_16x16x32_bf16(
                    aq[qt], bk[ni], (f32x4){0.f,0.f,0.f,0.f}, 0, 0, 0);

        // ---- masked online softmax, write P (bf16) ----
        #pragma unroll
        for (int qt = 0; qt < 2; qt++) {
            #pragma unroll
            for (int r = 0; r < 4; r++) {
                int qrow = w * 32 + qt * 16 + g * 4 + r;
                unsigned wd0 = Ms[qrow * 64 + tile * 2];
                unsigned wd1 = Ms[qrow * 64 + tile * 2 + 1];
                float sv[4];
                float mx = -1e30f;
                #pragma unroll
                for (int ni = 0; ni < 4; ni++) {
                    unsigned wdx = (ni < 2) ? wd0 : wd1;
                    unsigned bit = (wdx >> ((ni & 1) * 16 + l15)) & 1u;
                    sv[ni] = bit ? sfrag[qt][ni][r] : -1e30f;
                    mx = fmaxf(mx, sv[ni]);
                }
                mx = fmaxf(mx, __shfl_xor(mx, 1));
                mx = fmaxf(mx, __shfl_xor(mx, 2));
                mx = fmaxf(mx, __shfl_xor(mx, 4));
                mx = fmaxf(mx, __shfl_xor(mx, 8));
                float mnew = fmaxf(m_run[qt][r], mx);
                float corr = __expf(m_run[qt][r] - mnew);   // exp(-huge)=0, exp(0)=1; no NaN
                m_run[qt][r] = mnew;
                float rowsum = 0.f;
                #pragma unroll
                for (int ni = 0; ni < 4; ni++) {
                    float pv = __expf(sv[ni] - mnew);       // masked -> exp(-huge)=0
                    rowsum += pv;
                    Ps[qrow * 72 + ni * 16 + l15] = f2bf(pv);
                }
                rowsum += __shfl_xor(rowsum, 1);
                rowsum += __shfl_xor(rowsum, 2);
                rowsum += __shfl_xor(rowsum, 4);
                rowsum += __shfl_xor(rowsum, 8);
                l_run[qt][r] = l_run[qt][r] * corr + rowsum;
                accO[qt][0][r] *= corr;
                accO[qt][1][r] *= corr;
            }
        }

        // ---- PV: O[q 32][d 32] += P[q][kv 64] * V[kv][d] ----
        s16x8 ap0[2], ap1[2], bv0[2], bv1[2];
        #pragma unroll
        for (int qt = 0; qt < 2; qt++) {
            ap0[qt] = *(const s16x8*)&Ps[(w * 32 + qt * 16 + l15) * 72 + g * 8];
            ap1[qt] = *(const s16x8*)&Ps[(w * 32 + qt * 16 + l15) * 72 + 32 + g * 8];
        }
        #pragma unroll
        for (int dt = 0; dt < 2; dt++) {
            bv0[dt] = *(const s16x8*)&Vt[(dt * 16 + l15) * 72 + g * 8];
            bv1[dt] = *(const s16x8*)&Vt[(dt * 16 + l15) * 72 + 32 + g * 8];
        }
        #pragma unroll
        for (int qt = 0; qt < 2; qt++)
            #pragma unroll
            for (int dt = 0; dt < 2; dt++) {
                accO[qt][dt] = __builtin_amdgcn_mfma_f32_16x16x32_bf16(ap0[qt], bv0[dt], accO[qt][dt], 0, 0, 0);
                accO[qt][dt] = __builtin_amdgcn_mfma_f32_16x16x32_bf16(ap1[qt], bv1[dt], accO[qt][dt], 0, 0, 0);
            }
    }

    // ---- store partials ----
    size_t pbase = ((size_t)(b * 8 + h) * 8 + ch) * 128;
    #pragma unroll
    for (int qt = 0; qt < 2; qt++) {
        #pragma unroll
        for (int r = 0; r < 4; r++) {
            int qrow = w * 32 + qt * 16 + g * 4 + r;
            #pragma unroll
            for (int dt = 0; dt < 2; dt++)
                O_part[(pbase + qrow) * 32 + dt * 16 + l15] = accO[qt][dt][r];
            if (l15 == 0) {
                m_part[pbase + qrow] = m_run[qt][r];
                l_part[pbase + qrow] = l_run[qt][r];
            }
        }
    }
}

// ---------------- Combine partials: o[b][n][256] -------------------------------------
__global__ __launch_bounds__(256) void xattn_combine(
        const float* __restrict__ O_part, const float* __restrict__ m_part,
        const float* __restrict__ l_part, float* __restrict__ o) {
    int n = blockIdx.x;       // 0..99
    int b = blockIdx.y;
    int t = threadIdx.x;
    int h = t >> 5, d = t & 31;
    size_t base = ((size_t)(b * 8 + h)) * 8;
    float gm = -1e30f;
    #pragma unroll
    for (int ch = 0; ch < 8; ch++)
        gm = fmaxf(gm, m_part[(base + ch) * 128 + n]);
    float L = 0.f, acc = 0.f;
    #pragma unroll
    for (int ch = 0; ch < 8; ch++) {
        float e = __expf(m_part[(base + ch) * 128 + n] - gm);
        L += l_part[(base + ch) * 128 + n] * e;
        acc += O_part[((base + ch) * 128 + n) * 32 + d] * e;
    }
    o[((size_t)(b * 100 + n)) * 256 + t] = acc / L;
}

// ---------------- Self-attention over seq axis = b (8), one block per n -------------
__global__ void sattn_kernel(const float* __restrict__ qkv, float* __restrict__ so) {
    int n = blockIdx.x;
    int t = threadIdx.x;
    __shared__ float sq[8][256], sk[8][256], sv[8][256];
    __shared__ float S[512];   // [h][i][j]
    for (int idx = t; idx < 8 * 768; idx += 256) {
        int i = idx / 768, c = idx - i * 768;
        float v = qkv[((size_t)(i * NN + n)) * 768 + c];
        if (c < 256) sq[i][c] = v * SCALE;
        else if (c < 512) sk[i][c - 256] = v;
        else sv[i][c - 512] = v;
    }
    __syncthreads();
    for (int idx = t; idx < 512; idx += 256) {
        int h = idx >> 6, i = (idx >> 3) & 7, j = idx & 7;
        float acc = 0.0f;
        #pragma unroll
        for (int d = 0; d < 32; d++) acc += sq[i][h * 32 + d] * sk[j][h * 32 + d];
        S[idx] = acc;
    }
    __syncthreads();
    if (t < 64) {
        int h = t >> 3, i = t & 7;
        float* row = &S[h * 64 + i * 8];
        float mx = row[0];
        #pragma unroll
        for (int j = 1; j < 8; j++) mx = fmaxf(mx, row[j]);
        float sum = 0.0f;
        #pragma unroll
        for (int j = 0; j < 8; j++) { row[j] = __expf(row[j] - mx); sum += row[j]; }
        float inv = 1.0f / sum;
        #pragma unroll
        for (int j = 0; j < 8; j++) row[j] *= inv;
    }
    __syncthreads();
    int c = t, h = t >> 5;
    #pragma unroll
    for (int i = 0; i < 8; i++) {
        float acc = 0.0f;
        #pragma unroll
        for (int j = 0; j < 8; j++) acc += S[h * 64 + i * 8 + j] * sv[j][c];
        so[((size_t)(i * NN + n)) * 256 + c] = acc;
    }
}

extern "C" void kernel_launch(void* const* d_in, const int* in_sizes, int n_in,
                              void* d_out, int out_size, void* d_ws, size_t ws_size,
                              hipStream_t stream) {
    const float* x      = (const float*)d_in[0];
    const float* ctx    = (const float*)d_in[1];
    const int*   mask   = (const int*)  d_in[2];
    const float* mq_w   = (const float*)d_in[3];
    const float* mq_b   = (const float*)d_in[4];
    const float* mkv_w  = (const float*)d_in[5];
    const float* mkv_b  = (const float*)d_in[6];
    const float* mproj_w= (const float*)d_in[7];
    const float* mproj_b= (const float*)d_in[8];
    const float* in_w   = (const float*)d_in[9];
    const float* in_b   = (const float*)d_in[10];
    const float* out_w  = (const float*)d_in[11];
    const float* out_b  = (const float*)d_in[12];
    const float* w1     = (const float*)d_in[13];
    const float* b1     = (const float*)d_in[14];
    const float* w2     = (const float*)d_in[15];
    const float* b2     = (const float*)d_in[16];
    const float* n1_g   = (const float*)d_in[17];
    const float* n1_b   = (const float*)d_in[18];
    const float* n2_g   = (const float*)d_in[19];
    const float* n2_b   = (const float*)d_in[20];
    const float* n3_g   = (const float*)d_in[21];
    const float* n3_b   = (const float*)d_in[22];
    const float* n4_g   = (const float*)d_in[23];
    const float* n4_b   = (const float*)d_in[24];

    float* ws = (float*)d_ws;
    // fp32 workspace layout (floats)
    float* Y1  = ws + 0;         // 204800
    float* Q   = ws + 204800;    // 204800
    float* O   = ws + 409600;    // 204800
    float* X1  = ws + 614400;    // 204800
    float* Y2  = ws + 819200;    // 204800
    float* QKV = ws + 1024000;   // 614400
    float* SO  = ws + 1638400;   // 204800
    float* X2  = ws + 1843200;   // 204800
    float* Y3  = ws + 2048000;   // 204800
    float* F1  = ws + 2252800;   // 1638400
    float* X3  = ws + 3891200;   // 204800  -> ends at 4096000 floats (16,384,000 B)
    // transient region during attention (overlaps Y2..F1, which are dead then):
    unsigned* Mb     = (unsigned*)(ws + 819200);   // 524288 words  -> ends 1343488
    float*    O_part = ws + 1343488;               // 2097152       -> ends 3440640
    float*    m_part = ws + 3440640;               // 65536         -> ends 3506176
    float*    l_part = ws + 3506176;               // 65536         -> ends 3571712
    // Wkv_bf: live only steps 2.5..3 (before F1's step-11 lifetime) -> safe overlay
    ushort*   Wkv_bf = (ushort*)(ws + 3571712);    // 131072 ushorts = 65536 float slots
    ushort* Kh = (ushort*)((char*)d_ws + 16384000);            // 67,108,864 B
    ushort* Vh = (ushort*)((char*)d_ws + 16384000 + 67108864); // 67,108,864 B

    float* out = (float*)d_out;

    // 1) y1 = ln(x, n1)
    ln_kernel<<<ROWS, 256, 0, stream>>>(x, n1_g, n1_b, Y1);
    // 2) q = y1 @ mq_w.T + mq_b
    gemm_proj<false, false><<<dim3(13, 4), 256, 0, stream>>>(
        Y1, mq_w, mq_b, nullptr, Q, ROWS, 256, 256);
    // 2b) pre-convert mkv_w to bf16
    conv_bf16<<<128, 256, 0, stream>>>(mkv_w, Wkv_bf, 32768);
    // 3) kv = ctx @ mkv_w.T + mkv_b -> head-major bf16 K/V (XCD-grouped linear grid)
    gemm_kv<<<4096, 256, 0, stream>>>(ctx, Wkv_bf, mkv_b, Kh, Vh);
    // 3b) pack mask to bits
    pack_mask<<<(BB * 128 * MM) / 256, 256, 0, stream>>>(mask, Mb);
    // 4) flash cross-attention + combine
    {
        dim3 grid(8, HEADSS, BB);
        xattn_flash<<<grid, 256, 0, stream>>>(Q, Kh, Vh, Mb, O_part, m_part, l_part);
        dim3 cgrid(NN, BB);
        xattn_combine<<<cgrid, 256, 0, stream>>>(O_part, m_part, l_part, O);
    }
    // 5) x1 = x + o @ mproj_w.T + mproj_b
    gemm_proj<false, true><<<dim3(13, 4), 256, 0, stream>>>(
        O, mproj_w, mproj_b, x, X1, ROWS, 256, 256);
    // 6) y2 = ln(x1, n2)
    ln_kernel<<<ROWS, 256, 0, stream>>>(X1, n2_g, n2_b, Y2);
    // 7) qkv = y2 @ in_w.T + in_b
    gemm_proj<false, false><<<dim3(13, 12), 256, 0, stream>>>(
        Y2, in_w, in_b, nullptr, QKV, ROWS, 256, 768);
    // 8) self-attention over seq axis b
    sattn_kernel<<<NN, 256, 0, stream>>>(QKV, SO);
    // 9) x2 = x1 + so @ out_w.T + out_b
    gemm_proj<false, true><<<dim3(13, 4), 256, 0, stream>>>(
        SO, out_w, out_b, X1, X2, ROWS, 256, 256);
    // 10) y3 = ln(x2, n3)
    ln_kernel<<<ROWS, 256, 0, stream>>>(X2, n3_g, n3_b, Y3);
    // 11) f1 = gelu(y3 @ w1.T + b1)
    gemm_proj<true, false><<<dim3(13, 32), 256, 0, stream>>>(
        Y3, w1, b1, nullptr, F1, ROWS, 256, FFNN);
    // 12) x3 = x2 + f1 @ w2.T + b2
    gemm_proj<false, true><<<dim3(13, 4), 256, 0, stream>>>(
        F1, w2, b2, X2, X3, ROWS, FFNN, 256);
    // 13) out = ln(x3, n4)
    ln_kernel<<<ROWS, 256, 0, stream>>>(X3, n4_g, n4_b, out);
}

// Round 10
// 629.891 us; speedup vs baseline: 1.0273x; 1.0273x over previous
//
#include <hip/hip_runtime.h>
#include <hip/hip_bf16.h>

// Problem constants
#define BB 8
#define NN 100
#define DIMM 256
#define HEADSS 8
#define HDD 32
#define FFNN 2048
#define MM 16384               // H*W = 128*128
#define ROWS (BB*NN)           // 800
#define CTX_ROWS (BB*MM)       // 131072
#define SCALE 0.17677669529663689f   // 1/sqrt(32)

typedef __attribute__((ext_vector_type(8))) short s16x8;
typedef __attribute__((ext_vector_type(4))) float f32x4;

__device__ inline ushort f2bf(float f) {
    union { float f; unsigned u; } c; c.f = f;
    unsigned r = c.u + 0x7fffu + ((c.u >> 16) & 1u);
    return (ushort)(r >> 16);
}
__device__ inline float bf2f(ushort u) {
    union { unsigned i; float f; } c; c.i = ((unsigned)u) << 16; return c.f;
}

// ---------------- fp32 -> bf16 bulk convert (for weights) ----------------
__global__ __launch_bounds__(256) void conv_bf16(const float* __restrict__ src,
                                                 ushort* __restrict__ dst, int n4) {
    int i = blockIdx.x * 256 + threadIdx.x;
    if (i < n4) {
        float4 v = ((const float4*)src)[i];
        union { ushort u[4]; uint2 v2; } o;
        o.u[0] = f2bf(v.x); o.u[1] = f2bf(v.y); o.u[2] = f2bf(v.z); o.u[3] = f2bf(v.w);
        *(uint2*)&dst[i * 4] = o.v2;
    }
}

// ---------------- LayerNorm (dim=256), one block per row ----------------
__global__ void ln_kernel(const float* __restrict__ x, const float* __restrict__ g,
                          const float* __restrict__ beta, float* __restrict__ y) {
    int row = blockIdx.x;
    int t = threadIdx.x;
    float v = x[row * 256 + t];
    __shared__ float red[256];
    red[t] = v; __syncthreads();
    for (int s = 128; s > 0; s >>= 1) { if (t < s) red[t] += red[t + s]; __syncthreads(); }
    float mu = red[0] * (1.0f / 256.0f);
    __syncthreads();
    float d = v - mu;
    red[t] = d * d; __syncthreads();
    for (int s = 128; s > 0; s >>= 1) { if (t < s) red[t] += red[t + s]; __syncthreads(); }
    float var = red[0] * (1.0f / 256.0f);
    float r = rsqrtf(var + 1e-5f);
    y[row * 256 + t] = d * r * g[t] + beta[t];
}

// ---------------- MFMA projection GEMM: out[M][C] = act(A[M][K] @ W[C][K]^T + bias) (+res)
template<bool GELU, bool RES>
__global__ __launch_bounds__(256) void gemm_proj(const float* __restrict__ A,
                                                 const float* __restrict__ W,
                                                 const float* __restrict__ bias,
                                                 const float* __restrict__ res,
                                                 float* __restrict__ out,
                                                 int M, int K, int C) {
    int bm = blockIdx.x, bn = blockIdx.y;
    __shared__ __align__(16) ushort As[64 * 64];
    __shared__ __align__(16) ushort Bs[64 * 64];
    int t = threadIdx.x;
    int lane = t & 63, w = t >> 6;
    int wr = w >> 1, wc = w & 1;
    int l15 = lane & 15, lk = lane >> 4;
    int l7 = l15 & 7;

    f32x4 acc[2][2];
    #pragma unroll
    for (int i = 0; i < 2; i++)
        #pragma unroll
        for (int j = 0; j < 2; j++)
            acc[i][j] = (f32x4){0.f, 0.f, 0.f, 0.f};

    int srow = t >> 2;            // 0..63
    int sg0 = (t & 3) * 2;        // granule pair base: 0,2,4,6
    int swz0 = (sg0 ^ (srow & 7)) * 8;
    int swz1 = ((sg0 + 1) ^ (srow & 7)) * 8;
    int scol = sg0 * 8;           // global k offset 0,16,32,48

    int nkt = K >> 6;
    for (int kt = 0; kt < nkt; ++kt) {
        int kb = kt * 64 + scol;
        {
            int gr = bm * 64 + srow;
            s16x8 va0 = {0,0,0,0,0,0,0,0}, va1 = {0,0,0,0,0,0,0,0};
            if (gr < M) {
                const float* ap = A + (size_t)gr * K + kb;
                float4 a0 = *(const float4*)ap;
                float4 a1 = *(const float4*)(ap + 4);
                float4 a2 = *(const float4*)(ap + 8);
                float4 a3 = *(const float4*)(ap + 12);
                va0[0] = (short)f2bf(a0.x); va0[1] = (short)f2bf(a0.y);
                va0[2] = (short)f2bf(a0.z); va0[3] = (short)f2bf(a0.w);
                va0[4] = (short)f2bf(a1.x); va0[5] = (short)f2bf(a1.y);
                va0[6] = (short)f2bf(a1.z); va0[7] = (short)f2bf(a1.w);
                va1[0] = (short)f2bf(a2.x); va1[1] = (short)f2bf(a2.y);
                va1[2] = (short)f2bf(a2.z); va1[3] = (short)f2bf(a2.w);
                va1[4] = (short)f2bf(a3.x); va1[5] = (short)f2bf(a3.y);
                va1[6] = (short)f2bf(a3.z); va1[7] = (short)f2bf(a3.w);
            }
            *(s16x8*)&As[srow * 64 + swz0] = va0;
            *(s16x8*)&As[srow * 64 + swz1] = va1;
            const float* bp = W + (size_t)(bn * 64 + srow) * K + kb;
            float4 b0 = *(const float4*)bp;
            float4 b1 = *(const float4*)(bp + 4);
            float4 b2 = *(const float4*)(bp + 8);
            float4 b3 = *(const float4*)(bp + 12);
            s16x8 vb0, vb1;
            vb0[0] = (short)f2bf(b0.x); vb0[1] = (short)f2bf(b0.y);
            vb0[2] = (short)f2bf(b0.z); vb0[3] = (short)f2bf(b0.w);
            vb0[4] = (short)f2bf(b1.x); vb0[5] = (short)f2bf(b1.y);
            vb0[6] = (short)f2bf(b1.z); vb0[7] = (short)f2bf(b1.w);
            vb1[0] = (short)f2bf(b2.x); vb1[1] = (short)f2bf(b2.y);
            vb1[2] = (short)f2bf(b2.z); vb1[3] = (short)f2bf(b2.w);
            vb1[4] = (short)f2bf(b3.x); vb1[5] = (short)f2bf(b3.y);
            vb1[6] = (short)f2bf(b3.z); vb1[7] = (short)f2bf(b3.w);
            *(s16x8*)&Bs[srow * 64 + swz0] = vb0;
            *(s16x8*)&Bs[srow * 64 + swz1] = vb1;
        }
        __syncthreads();
        #pragma unroll
        for (int kk = 0; kk < 64; kk += 32) {
            int gsw = (((kk >> 3) + lk) ^ l7) * 8;
            s16x8 af[2], bf[2];
            #pragma unroll
            for (int mi = 0; mi < 2; mi++)
                af[mi] = *(const s16x8*)&As[(wr * 32 + mi * 16 + l15) * 64 + gsw];
            #pragma unroll
            for (int ni = 0; ni < 2; ni++)
                bf[ni] = *(const s16x8*)&Bs[(wc * 32 + ni * 16 + l15) * 64 + gsw];
            #pragma unroll
            for (int mi = 0; mi < 2; mi++)
                #pragma unroll
                for (int ni = 0; ni < 2; ni++)
                    acc[mi][ni] = __builtin_amdgcn_mfma_f32_16x16x32_bf16(af[mi], bf[ni], acc[mi][ni], 0, 0, 0);
        }
        __syncthreads();
    }
    #pragma unroll
    for (int ni = 0; ni < 2; ni++) {
        int col = bn * 64 + wc * 32 + ni * 16 + l15;
        float bv = bias[col];
        #pragma unroll
        for (int mi = 0; mi < 2; mi++) {
            int row0 = bm * 64 + wr * 32 + mi * 16 + lk * 4;
            #pragma unroll
            for (int r = 0; r < 4; r++) {
                int gr = row0 + r;
                if (gr < M) {
                    float v = acc[mi][ni][r] + bv;
                    if (GELU) v = 0.5f * v * (1.0f + erff(v * 0.70710678118654752f));
                    if (RES)  v += res[(size_t)gr * C + col];
                    out[(size_t)gr * C + col] = v;
                }
            }
        }
    }
}

// ---------------- KV projection v2: read-A-once full-strip GEMM ----------------
// Grid 1024 blocks (bm), 512 threads (8 waves, 2 row-halves x 4 col-quarters).
// Per block: output rows bm*128..+128, ALL 512 cols. A staged once per kt into LDS
// and reused by every column; bf16 weights (262 KB) stream from L2.
// LDS 80 KB: As[128][64] + Bs[512][64], XOR-granule swizzle (conflict-free, r6-verified).
// kt+1 global loads issued before the barrier (hide under 64-MFMA phase).
__global__ __launch_bounds__(512) void gemm_kv2(const float* __restrict__ A,
                                                const ushort* __restrict__ Wbf,
                                                const float* __restrict__ bias,
                                                ushort* __restrict__ Kh,
                                                ushort* __restrict__ Vh) {
    int bm = blockIdx.x;
    __shared__ __align__(16) ushort As[128 * 64];   // 16 KB
    __shared__ __align__(16) ushort Bs[512 * 64];   // 64 KB
    int t = threadIdx.x;
    int lane = t & 63, w = t >> 6;          // 8 waves
    int wr = w >> 2, wc = w & 3;            // 2 x 4
    int l15 = lane & 15, lk = lane >> 4;
    int l7 = l15 & 7;

    f32x4 acc[4][8];
    #pragma unroll
    for (int i = 0; i < 4; i++)
        #pragma unroll
        for (int j = 0; j < 8; j++)
            acc[i][j] = (f32x4){0.f, 0.f, 0.f, 0.f};

    // A staging: thread -> (row 0..127, k-quarter 0..3), 16 elems
    int arow = t >> 2;
    int aq = t & 3;
    int aswz0 = ((aq * 2)     ^ (arow & 7)) * 8;
    int aswz1 = ((aq * 2 + 1) ^ (arow & 7)) * 8;
    // B staging: thread -> (row (t>>3) + p*64, granule t&7); row&7 invariant under +64
    int brow = t >> 3;
    int bsg = t & 7;
    int bswz = (bsg ^ (brow & 7)) * 8;

    const float* Ab = A + (size_t)(bm * 128) * 256;

    float4 ra[4];
    uint4  rb[8];

    // prologue: issue kt=0 loads
    {
        const float* ap = Ab + (size_t)arow * 256 + aq * 16;
        ra[0] = *(const float4*)ap;       ra[1] = *(const float4*)(ap + 4);
        ra[2] = *(const float4*)(ap + 8); ra[3] = *(const float4*)(ap + 12);
        #pragma unroll
        for (int p = 0; p < 8; p++)
            rb[p] = *(const uint4*)(Wbf + (size_t)(p * 64 + brow) * 256 + bsg * 8);
    }

    for (int kt = 0; kt < 4; ++kt) {
        // stage current kt from registers
        {
            s16x8 va0, va1;
            va0[0] = (short)f2bf(ra[0].x); va0[1] = (short)f2bf(ra[0].y);
            va0[2] = (short)f2bf(ra[0].z); va0[3] = (short)f2bf(ra[0].w);
            va0[4] = (short)f2bf(ra[1].x); va0[5] = (short)f2bf(ra[1].y);
            va0[6] = (short)f2bf(ra[1].z); va0[7] = (short)f2bf(ra[1].w);
            va1[0] = (short)f2bf(ra[2].x); va1[1] = (short)f2bf(ra[2].y);
            va1[2] = (short)f2bf(ra[2].z); va1[3] = (short)f2bf(ra[2].w);
            va1[4] = (short)f2bf(ra[3].x); va1[5] = (short)f2bf(ra[3].y);
            va1[6] = (short)f2bf(ra[3].z); va1[7] = (short)f2bf(ra[3].w);
            *(s16x8*)&As[arow * 64 + aswz0] = va0;
            *(s16x8*)&As[arow * 64 + aswz1] = va1;
            #pragma unroll
            for (int p = 0; p < 8; p++)
                *(uint4*)&Bs[(p * 64 + brow) * 64 + bswz] = rb[p];
        }
        // issue kt+1 loads (in flight across barrier + MFMA)
        if (kt < 3) {
            int kb = (kt + 1) * 64;
            const float* ap = Ab + (size_t)arow * 256 + kb + aq * 16;
            ra[0] = *(const float4*)ap;       ra[1] = *(const float4*)(ap + 4);
            ra[2] = *(const float4*)(ap + 8); ra[3] = *(const float4*)(ap + 12);
            #pragma unroll
            for (int p = 0; p < 8; p++)
                rb[p] = *(const uint4*)(Wbf + (size_t)(p * 64 + brow) * 256 + kb + bsg * 8);
        }
        __syncthreads();
        #pragma unroll
        for (int kk = 0; kk < 64; kk += 32) {
            int gsw = (((kk >> 3) + lk) ^ l7) * 8;
            s16x8 af[4], bf8[8];
            #pragma unroll
            for (int mi = 0; mi < 4; mi++)
                af[mi] = *(const s16x8*)&As[(wr * 64 + mi * 16 + l15) * 64 + gsw];
            #pragma unroll
            for (int ni = 0; ni < 8; ni++)
                bf8[ni] = *(const s16x8*)&Bs[(wc * 128 + ni * 16 + l15) * 64 + gsw];
            #pragma unroll
            for (int mi = 0; mi < 4; mi++)
                #pragma unroll
                for (int ni = 0; ni < 8; ni++)
                    acc[mi][ni] = __builtin_amdgcn_mfma_f32_16x16x32_bf16(af[mi], bf8[ni], acc[mi][ni], 0, 0, 0);
        }
        __syncthreads();
    }

    // epilogue: ni innermost so both 32B halves of each 64B row-line store adjacently
    float bv[8];
    #pragma unroll
    for (int ni = 0; ni < 8; ni++)
        bv[ni] = bias[wc * 128 + ni * 16 + l15];
    #pragma unroll
    for (int mi = 0; mi < 4; mi++) {
        #pragma unroll
        for (int r = 0; r < 4; r++) {
            int gr = bm * 128 + wr * 64 + mi * 16 + lk * 4 + r;
            int b = gr >> 14, m = gr & 16383;
            size_t base = ((size_t)(b * 8) * 16384 + m) * 32;   // + h*16384*32 + hd per ni
            #pragma unroll
            for (int ni = 0; ni < 8; ni++) {
                int col = wc * 128 + ni * 16 + l15;
                int isV = col >> 8;
                int c2 = col & 255;
                int h = c2 >> 5, hd = c2 & 31;
                ushort* dst = isV ? Vh : Kh;
                dst[base + (size_t)h * 16384 * 32 + hd] = f2bf(acc[mi][ni][r] + bv[ni]);
            }
        }
    }
}

// ---------------- Mask bit-pack: Mb[b][n(128 padded)][512] uint32 --------------------
__global__ __launch_bounds__(256) void pack_mask(const int* __restrict__ mask,
                                                 unsigned* __restrict__ Mb) {
    unsigned tid = blockIdx.x * 256 + threadIdx.x;   // up to 2^24
    int b = tid >> 21;
    int rem = tid & ((1u << 21) - 1);
    int n = rem >> 14;
    int m = rem & 16383;
    int mv = 0;
    if (n < 100) mv = mask[(((size_t)b * 100 + n) << 14) + m];
    unsigned long long bal = __ballot(mv != 0);
    if ((threadIdx.x & 63) == 0) {
        size_t widx = (((size_t)b * 128 + n) << 9) + (m >> 5);   // even
        *(unsigned long long*)(Mb + widx) = bal;
    }
}

// ---------------- Flash masked cross-attention (MFMA) -------------------------------
__global__ __launch_bounds__(256) void xattn_flash(
        const float* __restrict__ q,          // [b][100][256]
        const ushort* __restrict__ Kh,        // [(b*8+h)][16384][32]
        const ushort* __restrict__ Vh,
        const unsigned* __restrict__ Mb,      // [b][128][512]
        float* __restrict__ O_part,           // [(b*8+h)*8+ch][128][32]
        float* __restrict__ m_part,           // [(b*8+h)*8+ch][128]
        float* __restrict__ l_part) {
    int ch = blockIdx.x;
    int h = blockIdx.y, b = blockIdx.z;
    int t = threadIdx.x;
    int lane = t & 63, w = t >> 6;
    int l15 = lane & 15, g = lane >> 4;

    __shared__ __align__(16) ushort Qs[128 * 40];   // 10240 B
    __shared__ __align__(16) ushort Ks[64 * 40];    // 5120 B
    __shared__ __align__(16) ushort Vt[32 * 72];    // 4608 B
    __shared__ __align__(16) ushort Ps[128 * 72];   // 18432 B
    __shared__ unsigned Ms[128 * 64];               // 32768 B

    {
        int r = t >> 1, dh = (t & 1) * 16;
        s16x8 v0 = {0,0,0,0,0,0,0,0}, v1 = {0,0,0,0,0,0,0,0};
        if (r < 100) {
            const float* qp = q + ((size_t)(b * 100 + r)) * 256 + h * 32 + dh;
            #pragma unroll
            for (int j = 0; j < 8; j++) v0[j] = (short)f2bf(qp[j] * SCALE);
            #pragma unroll
            for (int j = 0; j < 8; j++) v1[j] = (short)f2bf(qp[8 + j] * SCALE);
        }
        *(s16x8*)&Qs[r * 40 + dh] = v0;
        *(s16x8*)&Qs[r * 40 + dh + 8] = v1;
    }
    {
        const unsigned* mp = Mb + (((size_t)b * 128) << 9) + ch * 64;
        #pragma unroll
        for (int i = 0; i < 32; i++) {
            int idx = t + i * 256;
            int r = idx >> 6, wd = idx & 63;
            Ms[idx] = mp[((size_t)r << 9) + wd];
        }
    }
    __syncthreads();

    s16x8 aq[2];
    aq[0] = *(const s16x8*)&Qs[(w * 32 + l15) * 40 + g * 8];
    aq[1] = *(const s16x8*)&Qs[(w * 32 + 16 + l15) * 40 + g * 8];

    float m_run[2][4], l_run[2][4];
    f32x4 accO[2][2];
    #pragma unroll
    for (int qt = 0; qt < 2; qt++) {
        #pragma unroll
        for (int r = 0; r < 4; r++) { m_run[qt][r] = -1e30f; l_run[qt][r] = 0.f; }
        accO[qt][0] = (f32x4){0.f,0.f,0.f,0.f};
        accO[qt][1] = (f32x4){0.f,0.f,0.f,0.f};
    }

    const ushort* Kbase = Kh + (((size_t)(b * 8 + h)) * 16384 + (size_t)ch * 2048) * 32;
    const ushort* Vbase = Vh + (((size_t)(b * 8 + h)) * 16384 + (size_t)ch * 2048) * 32;

    for (int tile = 0; tile < 32; ++tile) {
        if (tile) __syncthreads();
        {
            int mrow = t >> 2, d0 = (t & 3) * 8;
            uint4 k4 = *(const uint4*)(Kbase + ((size_t)(tile * 64 + mrow)) * 32 + d0);
            *(uint4*)&Ks[mrow * 40 + d0] = k4;
            uint4 v4 = *(const uint4*)(Vbase + ((size_t)(tile * 64 + mrow)) * 32 + d0);
            const ushort* vsp = (const ushort*)&v4;
            #pragma unroll
            for (int j = 0; j < 8; j++) Vt[(d0 + j) * 72 + mrow] = vsp[j];
        }
        __syncthreads();

        s16x8 bk[4];
        #pragma unroll
        for (int ni = 0; ni < 4; ni++)
            bk[ni] = *(const s16x8*)&Ks[(ni * 16 + l15) * 40 + g * 8];
        f32x4 sfrag[2][4];
        #pragma unroll
        for (int qt = 0; qt < 2; qt++)
            #pragma unroll
            for (int ni = 0; ni < 4; ni++)
                sfrag[qt][ni] = __builtin_amdgcn_mfma_f32_16x16x32_bf16(
                    aq[qt], bk[ni], (f32x4){0.f,0.f,0.f,0.f}, 0, 0, 0);

        #pragma unroll
        for (int qt = 0; qt < 2; qt++) {
            #pragma unroll
            for (int r = 0; r < 4; r++) {
                int qrow = w * 32 + qt * 16 + g * 4 + r;
                unsigned wd0 = Ms[qrow * 64 + tile * 2];
                unsigned wd1 = Ms[qrow * 64 + tile * 2 + 1];
                float sv[4];
                float mx = -1e30f;
                #pragma unroll
                for (int ni = 0; ni < 4; ni++) {
                    unsigned wdx = (ni < 2) ? wd0 : wd1;
                    unsigned bit = (wdx >> ((ni & 1) * 16 + l15)) & 1u;
                    sv[ni] = bit ? sfrag[qt][ni][r] : -1e30f;
                    mx = fmaxf(mx, sv[ni]);
                }
                mx = fmaxf(mx, __shfl_xor(mx, 1));
                mx = fmaxf(mx, __shfl_xor(mx, 2));
                mx = fmaxf(mx, __shfl_xor(mx, 4));
                mx = fmaxf(mx, __shfl_xor(mx, 8));
                float mnew = fmaxf(m_run[qt][r], mx);
                float corr = __expf(m_run[qt][r] - mnew);
                m_run[qt][r] = mnew;
                float rowsum = 0.f;
                #pragma unroll
                for (int ni = 0; ni < 4; ni++) {
                    float pv = __expf(sv[ni] - mnew);
                    rowsum += pv;
                    Ps[qrow * 72 + ni * 16 + l15] = f2bf(pv);
                }
                rowsum += __shfl_xor(rowsum, 1);
                rowsum += __shfl_xor(rowsum, 2);
                rowsum += __shfl_xor(rowsum, 4);
                rowsum += __shfl_xor(rowsum, 8);
                l_run[qt][r] = l_run[qt][r] * corr + rowsum;
                accO[qt][0][r] *= corr;
                accO[qt][1][r] *= corr;
            }
        }

        s16x8 ap0[2], ap1[2], bv0[2], bv1[2];
        #pragma unroll
        for (int qt = 0; qt < 2; qt++) {
            ap0[qt] = *(const s16x8*)&Ps[(w * 32 + qt * 16 + l15) * 72 + g * 8];
            ap1[qt] = *(const s16x8*)&Ps[(w * 32 + qt * 16 + l15) * 72 + 32 + g * 8];
        }
        #pragma unroll
        for (int dt = 0; dt < 2; dt++) {
            bv0[dt] = *(const s16x8*)&Vt[(dt * 16 + l15) * 72 + g * 8];
            bv1[dt] = *(const s16x8*)&Vt[(dt * 16 + l15) * 72 + 32 + g * 8];
        }
        #pragma unroll
        for (int qt = 0; qt < 2; qt++)
            #pragma unroll
            for (int dt = 0; dt < 2; dt++) {
                accO[qt][dt] = __builtin_amdgcn_mfma_f32_16x16x32_bf16(ap0[qt], bv0[dt], accO[qt][dt], 0, 0, 0);
                accO[qt][dt] = __builtin_amdgcn_mfma_f32_16x16x32_bf16(ap1[qt], bv1[dt], accO[qt][dt], 0, 0, 0);
            }
    }

    size_t pbase = ((size_t)(b * 8 + h) * 8 + ch) * 128;
    #pragma unroll
    for (int qt = 0; qt < 2; qt++) {
        #pragma unroll
        for (int r = 0; r < 4; r++) {
            int qrow = w * 32 + qt * 16 + g * 4 + r;
            #pragma unroll
            for (int dt = 0; dt < 2; dt++)
                O_part[(pbase + qrow) * 32 + dt * 16 + l15] = accO[qt][dt][r];
            if (l15 == 0) {
                m_part[pbase + qrow] = m_run[qt][r];
                l_part[pbase + qrow] = l_run[qt][r];
            }
        }
    }
}

// ---------------- Combine partials: o[b][n][256] -------------------------------------
__global__ __launch_bounds__(256) void xattn_combine(
        const float* __restrict__ O_part, const float* __restrict__ m_part,
        const float* __restrict__ l_part, float* __restrict__ o) {
    int n = blockIdx.x;
    int b = blockIdx.y;
    int t = threadIdx.x;
    int h = t >> 5, d = t & 31;
    size_t base = ((size_t)(b * 8 + h)) * 8;
    float gm = -1e30f;
    #pragma unroll
    for (int ch = 0; ch < 8; ch++)
        gm = fmaxf(gm, m_part[(base + ch) * 128 + n]);
    float L = 0.f, acc = 0.f;
    #pragma unroll
    for (int ch = 0; ch < 8; ch++) {
        float e = __expf(m_part[(base + ch) * 128 + n] - gm);
        L += l_part[(base + ch) * 128 + n] * e;
        acc += O_part[((base + ch) * 128 + n) * 32 + d] * e;
    }
    o[((size_t)(b * 100 + n)) * 256 + t] = acc / L;
}

// ---------------- Self-attention over seq axis = b (8), one block per n -------------
__global__ void sattn_kernel(const float* __restrict__ qkv, float* __restrict__ so) {
    int n = blockIdx.x;
    int t = threadIdx.x;
    __shared__ float sq[8][256], sk[8][256], sv[8][256];
    __shared__ float S[512];   // [h][i][j]
    for (int idx = t; idx < 8 * 768; idx += 256) {
        int i = idx / 768, c = idx - i * 768;
        float v = qkv[((size_t)(i * NN + n)) * 768 + c];
        if (c < 256) sq[i][c] = v * SCALE;
        else if (c < 512) sk[i][c - 256] = v;
        else sv[i][c - 512] = v;
    }
    __syncthreads();
    for (int idx = t; idx < 512; idx += 256) {
        int h = idx >> 6, i = (idx >> 3) & 7, j = idx & 7;
        float acc = 0.0f;
        #pragma unroll
        for (int d = 0; d < 32; d++) acc += sq[i][h * 32 + d] * sk[j][h * 32 + d];
        S[idx] = acc;
    }
    __syncthreads();
    if (t < 64) {
        int h = t >> 3, i = t & 7;
        float* row = &S[h * 64 + i * 8];
        float mx = row[0];
        #pragma unroll
        for (int j = 1; j < 8; j++) mx = fmaxf(mx, row[j]);
        float sum = 0.0f;
        #pragma unroll
        for (int j = 0; j < 8; j++) { row[j] = __expf(row[j] - mx); sum += row[j]; }
        float inv = 1.0f / sum;
        #pragma unroll
        for (int j = 0; j < 8; j++) row[j] *= inv;
    }
    __syncthreads();
    int c = t, h = t >> 5;
    #pragma unroll
    for (int i = 0; i < 8; i++) {
        float acc = 0.0f;
        #pragma unroll
        for (int j = 0; j < 8; j++) acc += S[h * 64 + i * 8 + j] * sv[j][c];
        so[((size_t)(i * NN + n)) * 256 + c] = acc;
    }
}

extern "C" void kernel_launch(void* const* d_in, const int* in_sizes, int n_in,
                              void* d_out, int out_size, void* d_ws, size_t ws_size,
                              hipStream_t stream) {
    const float* x      = (const float*)d_in[0];
    const float* ctx    = (const float*)d_in[1];
    const int*   mask   = (const int*)  d_in[2];
    const float* mq_w   = (const float*)d_in[3];
    const float* mq_b   = (const float*)d_in[4];
    const float* mkv_w  = (const float*)d_in[5];
    const float* mkv_b  = (const float*)d_in[6];
    const float* mproj_w= (const float*)d_in[7];
    const float* mproj_b= (const float*)d_in[8];
    const float* in_w   = (const float*)d_in[9];
    const float* in_b   = (const float*)d_in[10];
    const float* out_w  = (const float*)d_in[11];
    const float* out_b  = (const float*)d_in[12];
    const float* w1     = (const float*)d_in[13];
    const float* b1     = (const float*)d_in[14];
    const float* w2     = (const float*)d_in[15];
    const float* b2     = (const float*)d_in[16];
    const float* n1_g   = (const float*)d_in[17];
    const float* n1_b   = (const float*)d_in[18];
    const float* n2_g   = (const float*)d_in[19];
    const float* n2_b   = (const float*)d_in[20];
    const float* n3_g   = (const float*)d_in[21];
    const float* n3_b   = (const float*)d_in[22];
    const float* n4_g   = (const float*)d_in[23];
    const float* n4_b   = (const float*)d_in[24];

    float* ws = (float*)d_ws;
    float* Y1  = ws + 0;         // 204800
    float* Q   = ws + 204800;    // 204800
    float* O   = ws + 409600;    // 204800
    float* X1  = ws + 614400;    // 204800
    float* Y2  = ws + 819200;    // 204800
    float* QKV = ws + 1024000;   // 614400
    float* SO  = ws + 1638400;   // 204800
    float* X2  = ws + 1843200;   // 204800
    float* Y3  = ws + 2048000;   // 204800
    float* F1  = ws + 2252800;   // 1638400
    float* X3  = ws + 3891200;   // 204800
    unsigned* Mb     = (unsigned*)(ws + 819200);   // transient during attention
    float*    O_part = ws + 1343488;
    float*    m_part = ws + 3440640;
    float*    l_part = ws + 3506176;
    ushort*   Wkv_bf = (ushort*)(ws + 3571712);
    ushort* Kh = (ushort*)((char*)d_ws + 16384000);
    ushort* Vh = (ushort*)((char*)d_ws + 16384000 + 67108864);

    float* out = (float*)d_out;

    // 1) y1 = ln(x, n1)
    ln_kernel<<<ROWS, 256, 0, stream>>>(x, n1_g, n1_b, Y1);
    // 2) q = y1 @ mq_w.T + mq_b
    gemm_proj<false, false><<<dim3(13, 4), 256, 0, stream>>>(
        Y1, mq_w, mq_b, nullptr, Q, ROWS, 256, 256);
    // 2b) pre-convert mkv_w to bf16
    conv_bf16<<<128, 256, 0, stream>>>(mkv_w, Wkv_bf, 32768);
    // 3) kv = ctx @ mkv_w.T + mkv_b -> head-major bf16 K/V (read-A-once strip GEMM)
    gemm_kv2<<<1024, 512, 0, stream>>>(ctx, Wkv_bf, mkv_b, Kh, Vh);
    // 3b) pack mask to bits
    pack_mask<<<(BB * 128 * MM) / 256, 256, 0, stream>>>(mask, Mb);
    // 4) flash cross-attention + combine
    {
        dim3 grid(8, HEADSS, BB);
        xattn_flash<<<grid, 256, 0, stream>>>(Q, Kh, Vh, Mb, O_part, m_part, l_part);
        dim3 cgrid(NN, BB);
        xattn_combine<<<cgrid, 256, 0, stream>>>(O_part, m_part, l_part, O);
    }
    // 5) x1 = x + o @ mproj_w.T + mproj_b
    gemm_proj<false, true><<<dim3(13, 4), 256, 0, stream>>>(
        O, mproj_w, mproj_b, x, X1, ROWS, 256, 256);
    // 6) y2 = ln(x1, n2)
    ln_kernel<<<ROWS, 256, 0, stream>>>(X1, n2_g, n2_b, Y2);
    // 7) qkv = y2 @ in_w.T + in_b
    gemm_proj<false, false><<<dim3(13, 12), 256, 0, stream>>>(
        Y2, in_w, in_b, nullptr, QKV, ROWS, 256, 768);
    // 8) self-attention over seq axis b
    sattn_kernel<<<NN, 256, 0, stream>>>(QKV, SO);
    // 9) x2 = x1 + so @ out_w.T + out_b
    gemm_proj<false, true><<<dim3(13, 4), 256, 0, stream>>>(
        SO, out_w, out_b, X1, X2, ROWS, 256, 256);
    // 10) y3 = ln(x2, n3)
    ln_kernel<<<ROWS, 256, 0, stream>>>(X2, n3_g, n3_b, Y3);
    // 11) f1 = gelu(y3 @ w1.T + b1)
    gemm_proj<true, false><<<dim3(13, 32), 256, 0, stream>>>(
        Y3, w1, b1, nullptr, F1, ROWS, 256, FFNN);
    // 12) x3 = x2 + f1 @ w2.T + b2
    gemm_proj<false, true><<<dim3(13, 4), 256, 0, stream>>>(
        F1, w2, b2, X2, X3, ROWS, FFNN, 256);
    // 13) out = ln(x3, n4)
    ln_kernel<<<ROWS, 256, 0, stream>>>(X3, n4_g, n4_b, out);
}

// Round 11
// 626.302 us; speedup vs baseline: 1.0332x; 1.0057x over previous
//
#include <hip/hip_runtime.h>
#include <hip/hip_bf16.h>

// Problem constants
#define BB 8
#define NN 100
#define DIMM 256
#define HEADSS 8
#define HDD 32
#define FFNN 2048
#define MM 16384               // H*W = 128*128
#define ROWS (BB*NN)           // 800
#define CTX_ROWS (BB*MM)       // 131072
#define SCALE 0.17677669529663689f   // 1/sqrt(32)
// K/V slice stride per (b,h): 16384*32 elems + 64-elem pad (128 B) to break the
// 1-MiB power-of-two L2 set aliasing across the 16 concurrently-written slices.
#define KVSLICE 524352

typedef __attribute__((ext_vector_type(8))) short s16x8;
typedef __attribute__((ext_vector_type(4))) float f32x4;

__device__ inline ushort f2bf(float f) {
    union { float f; unsigned u; } c; c.f = f;
    unsigned r = c.u + 0x7fffu + ((c.u >> 16) & 1u);
    return (ushort)(r >> 16);
}
__device__ inline float bf2f(ushort u) {
    union { unsigned i; float f; } c; c.i = ((unsigned)u) << 16; return c.f;
}

// ---------------- fp32 -> bf16 bulk convert (for weights) ----------------
__global__ __launch_bounds__(256) void conv_bf16(const float* __restrict__ src,
                                                 ushort* __restrict__ dst, int n4) {
    int i = blockIdx.x * 256 + threadIdx.x;
    if (i < n4) {
        float4 v = ((const float4*)src)[i];
        union { ushort u[4]; uint2 v2; } o;
        o.u[0] = f2bf(v.x); o.u[1] = f2bf(v.y); o.u[2] = f2bf(v.z); o.u[3] = f2bf(v.w);
        *(uint2*)&dst[i * 4] = o.v2;
    }
}

// ---------------- LayerNorm (dim=256), one block per row ----------------
__global__ void ln_kernel(const float* __restrict__ x, const float* __restrict__ g,
                          const float* __restrict__ beta, float* __restrict__ y) {
    int row = blockIdx.x;
    int t = threadIdx.x;
    float v = x[row * 256 + t];
    __shared__ float red[256];
    red[t] = v; __syncthreads();
    for (int s = 128; s > 0; s >>= 1) { if (t < s) red[t] += red[t + s]; __syncthreads(); }
    float mu = red[0] * (1.0f / 256.0f);
    __syncthreads();
    float d = v - mu;
    red[t] = d * d; __syncthreads();
    for (int s = 128; s > 0; s >>= 1) { if (t < s) red[t] += red[t + s]; __syncthreads(); }
    float var = red[0] * (1.0f / 256.0f);
    float r = rsqrtf(var + 1e-5f);
    y[row * 256 + t] = d * r * g[t] + beta[t];
}

// ---------------- MFMA projection GEMM: out[M][C] = act(A[M][K] @ W[C][K]^T + bias) (+res)
template<bool GELU, bool RES>
__global__ __launch_bounds__(256) void gemm_proj(const float* __restrict__ A,
                                                 const float* __restrict__ W,
                                                 const float* __restrict__ bias,
                                                 const float* __restrict__ res,
                                                 float* __restrict__ out,
                                                 int M, int K, int C) {
    int bm = blockIdx.x, bn = blockIdx.y;
    __shared__ __align__(16) ushort As[64 * 64];
    __shared__ __align__(16) ushort Bs[64 * 64];
    int t = threadIdx.x;
    int lane = t & 63, w = t >> 6;
    int wr = w >> 1, wc = w & 1;
    int l15 = lane & 15, lk = lane >> 4;
    int l7 = l15 & 7;

    f32x4 acc[2][2];
    #pragma unroll
    for (int i = 0; i < 2; i++)
        #pragma unroll
        for (int j = 0; j < 2; j++)
            acc[i][j] = (f32x4){0.f, 0.f, 0.f, 0.f};

    int srow = t >> 2;            // 0..63
    int sg0 = (t & 3) * 2;        // granule pair base: 0,2,4,6
    int swz0 = (sg0 ^ (srow & 7)) * 8;
    int swz1 = ((sg0 + 1) ^ (srow & 7)) * 8;
    int scol = sg0 * 8;           // global k offset 0,16,32,48

    int nkt = K >> 6;
    for (int kt = 0; kt < nkt; ++kt) {
        int kb = kt * 64 + scol;
        {
            int gr = bm * 64 + srow;
            s16x8 va0 = {0,0,0,0,0,0,0,0}, va1 = {0,0,0,0,0,0,0,0};
            if (gr < M) {
                const float* ap = A + (size_t)gr * K + kb;
                float4 a0 = *(const float4*)ap;
                float4 a1 = *(const float4*)(ap + 4);
                float4 a2 = *(const float4*)(ap + 8);
                float4 a3 = *(const float4*)(ap + 12);
                va0[0] = (short)f2bf(a0.x); va0[1] = (short)f2bf(a0.y);
                va0[2] = (short)f2bf(a0.z); va0[3] = (short)f2bf(a0.w);
                va0[4] = (short)f2bf(a1.x); va0[5] = (short)f2bf(a1.y);
                va0[6] = (short)f2bf(a1.z); va0[7] = (short)f2bf(a1.w);
                va1[0] = (short)f2bf(a2.x); va1[1] = (short)f2bf(a2.y);
                va1[2] = (short)f2bf(a2.z); va1[3] = (short)f2bf(a2.w);
                va1[4] = (short)f2bf(a3.x); va1[5] = (short)f2bf(a3.y);
                va1[6] = (short)f2bf(a3.z); va1[7] = (short)f2bf(a3.w);
            }
            *(s16x8*)&As[srow * 64 + swz0] = va0;
            *(s16x8*)&As[srow * 64 + swz1] = va1;
            const float* bp = W + (size_t)(bn * 64 + srow) * K + kb;
            float4 b0 = *(const float4*)bp;
            float4 b1 = *(const float4*)(bp + 4);
            float4 b2 = *(const float4*)(bp + 8);
            float4 b3 = *(const float4*)(bp + 12);
            s16x8 vb0, vb1;
            vb0[0] = (short)f2bf(b0.x); vb0[1] = (short)f2bf(b0.y);
            vb0[2] = (short)f2bf(b0.z); vb0[3] = (short)f2bf(b0.w);
            vb0[4] = (short)f2bf(b1.x); vb0[5] = (short)f2bf(b1.y);
            vb0[6] = (short)f2bf(b1.z); vb0[7] = (short)f2bf(b1.w);
            vb1[0] = (short)f2bf(b2.x); vb1[1] = (short)f2bf(b2.y);
            vb1[2] = (short)f2bf(b2.z); vb1[3] = (short)f2bf(b2.w);
            vb1[4] = (short)f2bf(b3.x); vb1[5] = (short)f2bf(b3.y);
            vb1[6] = (short)f2bf(b3.z); vb1[7] = (short)f2bf(b3.w);
            *(s16x8*)&Bs[srow * 64 + swz0] = vb0;
            *(s16x8*)&Bs[srow * 64 + swz1] = vb1;
        }
        __syncthreads();
        #pragma unroll
        for (int kk = 0; kk < 64; kk += 32) {
            int gsw = (((kk >> 3) + lk) ^ l7) * 8;
            s16x8 af[2], bf[2];
            #pragma unroll
            for (int mi = 0; mi < 2; mi++)
                af[mi] = *(const s16x8*)&As[(wr * 32 + mi * 16 + l15) * 64 + gsw];
            #pragma unroll
            for (int ni = 0; ni < 2; ni++)
                bf[ni] = *(const s16x8*)&Bs[(wc * 32 + ni * 16 + l15) * 64 + gsw];
            #pragma unroll
            for (int mi = 0; mi < 2; mi++)
                #pragma unroll
                for (int ni = 0; ni < 2; ni++)
                    acc[mi][ni] = __builtin_amdgcn_mfma_f32_16x16x32_bf16(af[mi], bf[ni], acc[mi][ni], 0, 0, 0);
        }
        __syncthreads();
    }
    #pragma unroll
    for (int ni = 0; ni < 2; ni++) {
        int col = bn * 64 + wc * 32 + ni * 16 + l15;
        float bv = bias[col];
        #pragma unroll
        for (int mi = 0; mi < 2; mi++) {
            int row0 = bm * 64 + wr * 32 + mi * 16 + lk * 4;
            #pragma unroll
            for (int r = 0; r < 4; r++) {
                int gr = row0 + r;
                if (gr < M) {
                    float v = acc[mi][ni][r] + bv;
                    if (GELU) v = 0.5f * v * (1.0f + erff(v * 0.70710678118654752f));
                    if (RES)  v += res[(size_t)gr * C + col];
                    out[(size_t)gr * C + col] = v;
                }
            }
        }
    }
}

// ---------------- KV projection v2: read-A-once full-strip GEMM ----------------
// Grid 1024 blocks (bm), 512 threads (8 waves, 2 row-halves x 4 col-quarters).
// K/V slices padded to KVSLICE to break 1-MiB L2 set aliasing (write-amp fix).
__global__ __launch_bounds__(512) void gemm_kv2(const float* __restrict__ A,
                                                const ushort* __restrict__ Wbf,
                                                const float* __restrict__ bias,
                                                ushort* __restrict__ Kh,
                                                ushort* __restrict__ Vh) {
    int bm = blockIdx.x;
    __shared__ __align__(16) ushort As[128 * 64];   // 16 KB
    __shared__ __align__(16) ushort Bs[512 * 64];   // 64 KB
    int t = threadIdx.x;
    int lane = t & 63, w = t >> 6;          // 8 waves
    int wr = w >> 2, wc = w & 3;            // 2 x 4
    int l15 = lane & 15, lk = lane >> 4;
    int l7 = l15 & 7;

    f32x4 acc[4][8];
    #pragma unroll
    for (int i = 0; i < 4; i++)
        #pragma unroll
        for (int j = 0; j < 8; j++)
            acc[i][j] = (f32x4){0.f, 0.f, 0.f, 0.f};

    int arow = t >> 2;
    int aq = t & 3;
    int aswz0 = ((aq * 2)     ^ (arow & 7)) * 8;
    int aswz1 = ((aq * 2 + 1) ^ (arow & 7)) * 8;
    int brow = t >> 3;
    int bsg = t & 7;
    int bswz = (bsg ^ (brow & 7)) * 8;

    const float* Ab = A + (size_t)(bm * 128) * 256;

    float4 ra[4];
    uint4  rb[8];

    {
        const float* ap = Ab + (size_t)arow * 256 + aq * 16;
        ra[0] = *(const float4*)ap;       ra[1] = *(const float4*)(ap + 4);
        ra[2] = *(const float4*)(ap + 8); ra[3] = *(const float4*)(ap + 12);
        #pragma unroll
        for (int p = 0; p < 8; p++)
            rb[p] = *(const uint4*)(Wbf + (size_t)(p * 64 + brow) * 256 + bsg * 8);
    }

    for (int kt = 0; kt < 4; ++kt) {
        {
            s16x8 va0, va1;
            va0[0] = (short)f2bf(ra[0].x); va0[1] = (short)f2bf(ra[0].y);
            va0[2] = (short)f2bf(ra[0].z); va0[3] = (short)f2bf(ra[0].w);
            va0[4] = (short)f2bf(ra[1].x); va0[5] = (short)f2bf(ra[1].y);
            va0[6] = (short)f2bf(ra[1].z); va0[7] = (short)f2bf(ra[1].w);
            va1[0] = (short)f2bf(ra[2].x); va1[1] = (short)f2bf(ra[2].y);
            va1[2] = (short)f2bf(ra[2].z); va1[3] = (short)f2bf(ra[2].w);
            va1[4] = (short)f2bf(ra[3].x); va1[5] = (short)f2bf(ra[3].y);
            va1[6] = (short)f2bf(ra[3].z); va1[7] = (short)f2bf(ra[3].w);
            *(s16x8*)&As[arow * 64 + aswz0] = va0;
            *(s16x8*)&As[arow * 64 + aswz1] = va1;
            #pragma unroll
            for (int p = 0; p < 8; p++)
                *(uint4*)&Bs[(p * 64 + brow) * 64 + bswz] = rb[p];
        }
        if (kt < 3) {
            int kb = (kt + 1) * 64;
            const float* ap = Ab + (size_t)arow * 256 + kb + aq * 16;
            ra[0] = *(const float4*)ap;       ra[1] = *(const float4*)(ap + 4);
            ra[2] = *(const float4*)(ap + 8); ra[3] = *(const float4*)(ap + 12);
            #pragma unroll
            for (int p = 0; p < 8; p++)
                rb[p] = *(const uint4*)(Wbf + (size_t)(p * 64 + brow) * 256 + kb + bsg * 8);
        }
        __syncthreads();
        #pragma unroll
        for (int kk = 0; kk < 64; kk += 32) {
            int gsw = (((kk >> 3) + lk) ^ l7) * 8;
            s16x8 af[4], bf8[8];
            #pragma unroll
            for (int mi = 0; mi < 4; mi++)
                af[mi] = *(const s16x8*)&As[(wr * 64 + mi * 16 + l15) * 64 + gsw];
            #pragma unroll
            for (int ni = 0; ni < 8; ni++)
                bf8[ni] = *(const s16x8*)&Bs[(wc * 128 + ni * 16 + l15) * 64 + gsw];
            #pragma unroll
            for (int mi = 0; mi < 4; mi++)
                #pragma unroll
                for (int ni = 0; ni < 8; ni++)
                    acc[mi][ni] = __builtin_amdgcn_mfma_f32_16x16x32_bf16(af[mi], bf8[ni], acc[mi][ni], 0, 0, 0);
        }
        __syncthreads();
    }

    // epilogue: padded-slice stores (ni innermost)
    float bv[8];
    #pragma unroll
    for (int ni = 0; ni < 8; ni++)
        bv[ni] = bias[wc * 128 + ni * 16 + l15];
    #pragma unroll
    for (int mi = 0; mi < 4; mi++) {
        #pragma unroll
        for (int r = 0; r < 4; r++) {
            int gr = bm * 128 + wr * 64 + mi * 16 + lk * 4 + r;
            int b = gr >> 14, m = gr & 16383;
            #pragma unroll
            for (int ni = 0; ni < 8; ni++) {
                int col = wc * 128 + ni * 16 + l15;
                int isV = col >> 8;
                int c2 = col & 255;
                int h = c2 >> 5, hd = c2 & 31;
                ushort* dst = isV ? Vh : Kh;
                dst[(size_t)(b * 8 + h) * KVSLICE + (size_t)m * 32 + hd] =
                    f2bf(acc[mi][ni][r] + bv[ni]);
            }
        }
    }
}

// ---------------- Mask bit-pack: Mb[b][n(128 padded)][512] uint32 --------------------
__global__ __launch_bounds__(256) void pack_mask(const int* __restrict__ mask,
                                                 unsigned* __restrict__ Mb) {
    unsigned tid = blockIdx.x * 256 + threadIdx.x;   // up to 2^24
    int b = tid >> 21;
    int rem = tid & ((1u << 21) - 1);
    int n = rem >> 14;
    int m = rem & 16383;
    int mv = 0;
    if (n < 100) mv = mask[(((size_t)b * 100 + n) << 14) + m];
    unsigned long long bal = __ballot(mv != 0);
    if ((threadIdx.x & 63) == 0) {
        size_t widx = (((size_t)b * 128 + n) << 9) + (m >> 5);   // even
        *(unsigned long long*)(Mb + widx) = bal;
    }
}

// ---------------- Flash masked cross-attention (MFMA) -------------------------------
__global__ __launch_bounds__(256) void xattn_flash(
        const float* __restrict__ q,          // [b][100][256]
        const ushort* __restrict__ Kh,        // [(b*8+h)][KVSLICE] bf16
        const ushort* __restrict__ Vh,
        const unsigned* __restrict__ Mb,      // [b][128][512]
        float* __restrict__ O_part,           // [(b*8+h)*8+ch][128][32]
        float* __restrict__ m_part,           // [(b*8+h)*8+ch][128]
        float* __restrict__ l_part) {
    int ch = blockIdx.x;
    int h = blockIdx.y, b = blockIdx.z;
    int t = threadIdx.x;
    int lane = t & 63, w = t >> 6;
    int l15 = lane & 15, g = lane >> 4;

    __shared__ __align__(16) ushort Qs[128 * 40];   // 10240 B
    __shared__ __align__(16) ushort Ks[64 * 40];    // 5120 B
    __shared__ __align__(16) ushort Vt[32 * 72];    // 4608 B
    __shared__ __align__(16) ushort Ps[128 * 72];   // 18432 B
    __shared__ unsigned Ms[128 * 64];               // 32768 B

    {
        int r = t >> 1, dh = (t & 1) * 16;
        s16x8 v0 = {0,0,0,0,0,0,0,0}, v1 = {0,0,0,0,0,0,0,0};
        if (r < 100) {
            const float* qp = q + ((size_t)(b * 100 + r)) * 256 + h * 32 + dh;
            #pragma unroll
            for (int j = 0; j < 8; j++) v0[j] = (short)f2bf(qp[j] * SCALE);
            #pragma unroll
            for (int j = 0; j < 8; j++) v1[j] = (short)f2bf(qp[8 + j] * SCALE);
        }
        *(s16x8*)&Qs[r * 40 + dh] = v0;
        *(s16x8*)&Qs[r * 40 + dh + 8] = v1;
    }
    {
        const unsigned* mp = Mb + (((size_t)b * 128) << 9) + ch * 64;
        #pragma unroll
        for (int i = 0; i < 32; i++) {
            int idx = t + i * 256;
            int r = idx >> 6, wd = idx & 63;
            Ms[idx] = mp[((size_t)r << 9) + wd];
        }
    }
    __syncthreads();

    s16x8 aq[2];
    aq[0] = *(const s16x8*)&Qs[(w * 32 + l15) * 40 + g * 8];
    aq[1] = *(const s16x8*)&Qs[(w * 32 + 16 + l15) * 40 + g * 8];

    float m_run[2][4], l_run[2][4];
    f32x4 accO[2][2];
    #pragma unroll
    for (int qt = 0; qt < 2; qt++) {
        #pragma unroll
        for (int r = 0; r < 4; r++) { m_run[qt][r] = -1e30f; l_run[qt][r] = 0.f; }
        accO[qt][0] = (f32x4){0.f,0.f,0.f,0.f};
        accO[qt][1] = (f32x4){0.f,0.f,0.f,0.f};
    }

    const ushort* Kbase = Kh + (size_t)(b * 8 + h) * KVSLICE + (size_t)ch * 2048 * 32;
    const ushort* Vbase = Vh + (size_t)(b * 8 + h) * KVSLICE + (size_t)ch * 2048 * 32;

    for (int tile = 0; tile < 32; ++tile) {
        if (tile) __syncthreads();
        {
            int mrow = t >> 2, d0 = (t & 3) * 8;
            uint4 k4 = *(const uint4*)(Kbase + ((size_t)(tile * 64 + mrow)) * 32 + d0);
            *(uint4*)&Ks[mrow * 40 + d0] = k4;
            uint4 v4 = *(const uint4*)(Vbase + ((size_t)(tile * 64 + mrow)) * 32 + d0);
            const ushort* vsp = (const ushort*)&v4;
            #pragma unroll
            for (int j = 0; j < 8; j++) Vt[(d0 + j) * 72 + mrow] = vsp[j];
        }
        __syncthreads();

        s16x8 bk[4];
        #pragma unroll
        for (int ni = 0; ni < 4; ni++)
            bk[ni] = *(const s16x8*)&Ks[(ni * 16 + l15) * 40 + g * 8];
        f32x4 sfrag[2][4];
        #pragma unroll
        for (int qt = 0; qt < 2; qt++)
            #pragma unroll
            for (int ni = 0; ni < 4; ni++)
                sfrag[qt][ni] = __builtin_amdgcn_mfma_f32_16x16x32_bf16(
                    aq[qt], bk[ni], (f32x4){0.f,0.f,0.f,0.f}, 0, 0, 0);

        #pragma unroll
        for (int qt = 0; qt < 2; qt++) {
            #pragma unroll
            for (int r = 0; r < 4; r++) {
                int qrow = w * 32 + qt * 16 + g * 4 + r;
                unsigned wd0 = Ms[qrow * 64 + tile * 2];
                unsigned wd1 = Ms[qrow * 64 + tile * 2 + 1];
                float sv[4];
                float mx = -1e30f;
                #pragma unroll
                for (int ni = 0; ni < 4; ni++) {
                    unsigned wdx = (ni < 2) ? wd0 : wd1;
                    unsigned bit = (wdx >> ((ni & 1) * 16 + l15)) & 1u;
                    sv[ni] = bit ? sfrag[qt][ni][r] : -1e30f;
                    mx = fmaxf(mx, sv[ni]);
                }
                mx = fmaxf(mx, __shfl_xor(mx, 1));
                mx = fmaxf(mx, __shfl_xor(mx, 2));
                mx = fmaxf(mx, __shfl_xor(mx, 4));
                mx = fmaxf(mx, __shfl_xor(mx, 8));
                float mnew = fmaxf(m_run[qt][r], mx);
                float corr = __expf(m_run[qt][r] - mnew);
                m_run[qt][r] = mnew;
                float rowsum = 0.f;
                #pragma unroll
                for (int ni = 0; ni < 4; ni++) {
                    float pv = __expf(sv[ni] - mnew);
                    rowsum += pv;
                    Ps[qrow * 72 + ni * 16 + l15] = f2bf(pv);
                }
                rowsum += __shfl_xor(rowsum, 1);
                rowsum += __shfl_xor(rowsum, 2);
                rowsum += __shfl_xor(rowsum, 4);
                rowsum += __shfl_xor(rowsum, 8);
                l_run[qt][r] = l_run[qt][r] * corr + rowsum;
                accO[qt][0][r] *= corr;
                accO[qt][1][r] *= corr;
            }
        }

        s16x8 ap0[2], ap1[2], bv0[2], bv1[2];
        #pragma unroll
        for (int qt = 0; qt < 2; qt++) {
            ap0[qt] = *(const s16x8*)&Ps[(w * 32 + qt * 16 + l15) * 72 + g * 8];
            ap1[qt] = *(const s16x8*)&Ps[(w * 32 + qt * 16 + l15) * 72 + 32 + g * 8];
        }
        #pragma unroll
        for (int dt = 0; dt < 2; dt++) {
            bv0[dt] = *(const s16x8*)&Vt[(dt * 16 + l15) * 72 + g * 8];
            bv1[dt] = *(const s16x8*)&Vt[(dt * 16 + l15) * 72 + 32 + g * 8];
        }
        #pragma unroll
        for (int qt = 0; qt < 2; qt++)
            #pragma unroll
            for (int dt = 0; dt < 2; dt++) {
                accO[qt][dt] = __builtin_amdgcn_mfma_f32_16x16x32_bf16(ap0[qt], bv0[dt], accO[qt][dt], 0, 0, 0);
                accO[qt][dt] = __builtin_amdgcn_mfma_f32_16x16x32_bf16(ap1[qt], bv1[dt], accO[qt][dt], 0, 0, 0);
            }
    }

    size_t pbase = ((size_t)(b * 8 + h) * 8 + ch) * 128;
    #pragma unroll
    for (int qt = 0; qt < 2; qt++) {
        #pragma unroll
        for (int r = 0; r < 4; r++) {
            int qrow = w * 32 + qt * 16 + g * 4 + r;
            #pragma unroll
            for (int dt = 0; dt < 2; dt++)
                O_part[(pbase + qrow) * 32 + dt * 16 + l15] = accO[qt][dt][r];
            if (l15 == 0) {
                m_part[pbase + qrow] = m_run[qt][r];
                l_part[pbase + qrow] = l_run[qt][r];
            }
        }
    }
}

// ---------------- Combine partials: o[b][n][256] -------------------------------------
__global__ __launch_bounds__(256) void xattn_combine(
        const float* __restrict__ O_part, const float* __restrict__ m_part,
        const float* __restrict__ l_part, float* __restrict__ o) {
    int n = blockIdx.x;
    int b = blockIdx.y;
    int t = threadIdx.x;
    int h = t >> 5, d = t & 31;
    size_t base = ((size_t)(b * 8 + h)) * 8;
    float gm = -1e30f;
    #pragma unroll
    for (int ch = 0; ch < 8; ch++)
        gm = fmaxf(gm, m_part[(base + ch) * 128 + n]);
    float L = 0.f, acc = 0.f;
    #pragma unroll
    for (int ch = 0; ch < 8; ch++) {
        float e = __expf(m_part[(base + ch) * 128 + n] - gm);
        L += l_part[(base + ch) * 128 + n] * e;
        acc += O_part[((base + ch) * 128 + n) * 32 + d] * e;
    }
    o[((size_t)(b * 100 + n)) * 256 + t] = acc / L;
}

// ---------------- Self-attention over seq axis = b (8), one block per n -------------
__global__ void sattn_kernel(const float* __restrict__ qkv, float* __restrict__ so) {
    int n = blockIdx.x;
    int t = threadIdx.x;
    __shared__ float sq[8][256], sk[8][256], sv[8][256];
    __shared__ float S[512];   // [h][i][j]
    for (int idx = t; idx < 8 * 768; idx += 256) {
        int i = idx / 768, c = idx - i * 768;
        float v = qkv[((size_t)(i * NN + n)) * 768 + c];
        if (c < 256) sq[i][c] = v * SCALE;
        else if (c < 512) sk[i][c - 256] = v;
        else sv[i][c - 512] = v;
    }
    __syncthreads();
    for (int idx = t; idx < 512; idx += 256) {
        int h = idx >> 6, i = (idx >> 3) & 7, j = idx & 7;
        float acc = 0.0f;
        #pragma unroll
        for (int d = 0; d < 32; d++) acc += sq[i][h * 32 + d] * sk[j][h * 32 + d];
        S[idx] = acc;
    }
    __syncthreads();
    if (t < 64) {
        int h = t >> 3, i = t & 7;
        float* row = &S[h * 64 + i * 8];
        float mx = row[0];
        #pragma unroll
        for (int j = 1; j < 8; j++) mx = fmaxf(mx, row[j]);
        float sum = 0.0f;
        #pragma unroll
        for (int j = 0; j < 8; j++) { row[j] = __expf(row[j] - mx); sum += row[j]; }
        float inv = 1.0f / sum;
        #pragma unroll
        for (int j = 0; j < 8; j++) row[j] *= inv;
    }
    __syncthreads();
    int c = t, h = t >> 5;
    #pragma unroll
    for (int i = 0; i < 8; i++) {
        float acc = 0.0f;
        #pragma unroll
        for (int j = 0; j < 8; j++) acc += S[h * 64 + i * 8 + j] * sv[j][c];
        so[((size_t)(i * NN + n)) * 256 + c] = acc;
    }
}

extern "C" void kernel_launch(void* const* d_in, const int* in_sizes, int n_in,
                              void* d_out, int out_size, void* d_ws, size_t ws_size,
                              hipStream_t stream) {
    const float* x      = (const float*)d_in[0];
    const float* ctx    = (const float*)d_in[1];
    const int*   mask   = (const int*)  d_in[2];
    const float* mq_w   = (const float*)d_in[3];
    const float* mq_b   = (const float*)d_in[4];
    const float* mkv_w  = (const float*)d_in[5];
    const float* mkv_b  = (const float*)d_in[6];
    const float* mproj_w= (const float*)d_in[7];
    const float* mproj_b= (const float*)d_in[8];
    const float* in_w   = (const float*)d_in[9];
    const float* in_b   = (const float*)d_in[10];
    const float* out_w  = (const float*)d_in[11];
    const float* out_b  = (const float*)d_in[12];
    const float* w1     = (const float*)d_in[13];
    const float* b1     = (const float*)d_in[14];
    const float* w2     = (const float*)d_in[15];
    const float* b2     = (const float*)d_in[16];
    const float* n1_g   = (const float*)d_in[17];
    const float* n1_b   = (const float*)d_in[18];
    const float* n2_g   = (const float*)d_in[19];
    const float* n2_b   = (const float*)d_in[20];
    const float* n3_g   = (const float*)d_in[21];
    const float* n3_b   = (const float*)d_in[22];
    const float* n4_g   = (const float*)d_in[23];
    const float* n4_b   = (const float*)d_in[24];

    float* ws = (float*)d_ws;
    float* Y1  = ws + 0;         // 204800
    float* Q   = ws + 204800;    // 204800
    float* O   = ws + 409600;    // 204800
    float* X1  = ws + 614400;    // 204800
    float* Y2  = ws + 819200;    // 204800
    float* QKV = ws + 1024000;   // 614400
    float* SO  = ws + 1638400;   // 204800
    float* X2  = ws + 1843200;   // 204800
    float* Y3  = ws + 2048000;   // 204800
    float* F1  = ws + 2252800;   // 1638400
    float* X3  = ws + 3891200;   // 204800
    unsigned* Mb     = (unsigned*)(ws + 819200);   // transient during attention
    float*    O_part = ws + 1343488;
    float*    m_part = ws + 3440640;
    float*    l_part = ws + 3506176;
    ushort*   Wkv_bf = (ushort*)(ws + 3571712);
    // padded K/V: 64 slices x KVSLICE bf16 each = 67,117,056 B per tensor
    ushort* Kh = (ushort*)((char*)d_ws + 16384000);
    ushort* Vh = (ushort*)((char*)d_ws + 16384000 + 67117056);

    float* out = (float*)d_out;

    // 1) y1 = ln(x, n1)
    ln_kernel<<<ROWS, 256, 0, stream>>>(x, n1_g, n1_b, Y1);
    // 2) q = y1 @ mq_w.T + mq_b
    gemm_proj<false, false><<<dim3(13, 4), 256, 0, stream>>>(
        Y1, mq_w, mq_b, nullptr, Q, ROWS, 256, 256);
    // 2b) pre-convert mkv_w to bf16
    conv_bf16<<<128, 256, 0, stream>>>(mkv_w, Wkv_bf, 32768);
    // 3) kv = ctx @ mkv_w.T + mkv_b -> head-major padded bf16 K/V
    gemm_kv2<<<1024, 512, 0, stream>>>(ctx, Wkv_bf, mkv_b, Kh, Vh);
    // 3b) pack mask to bits
    pack_mask<<<(BB * 128 * MM) / 256, 256, 0, stream>>>(mask, Mb);
    // 4) flash cross-attention + combine
    {
        dim3 grid(8, HEADSS, BB);
        xattn_flash<<<grid, 256, 0, stream>>>(Q, Kh, Vh, Mb, O_part, m_part, l_part);
        dim3 cgrid(NN, BB);
        xattn_combine<<<cgrid, 256, 0, stream>>>(O_part, m_part, l_part, O);
    }
    // 5) x1 = x + o @ mproj_w.T + mproj_b
    gemm_proj<false, true><<<dim3(13, 4), 256, 0, stream>>>(
        O, mproj_w, mproj_b, x, X1, ROWS, 256, 256);
    // 6) y2 = ln(x1, n2)
    ln_kernel<<<ROWS, 256, 0, stream>>>(X1, n2_g, n2_b, Y2);
    // 7) qkv = y2 @ in_w.T + in_b
    gemm_proj<false, false><<<dim3(13, 12), 256, 0, stream>>>(
        Y2, in_w, in_b, nullptr, QKV, ROWS, 256, 768);
    // 8) self-attention over seq axis b
    sattn_kernel<<<NN, 256, 0, stream>>>(QKV, SO);
    // 9) x2 = x1 + so @ out_w.T + out_b
    gemm_proj<false, true><<<dim3(13, 4), 256, 0, stream>>>(
        SO, out_w, out_b, X1, X2, ROWS, 256, 256);
    // 10) y3 = ln(x2, n3)
    ln_kernel<<<ROWS, 256, 0, stream>>>(X2, n3_g, n3_b, Y3);
    // 11) f1 = gelu(y3 @ w1.T + b1)
    gemm_proj<true, false><<<dim3(13, 32), 256, 0, stream>>>(
        Y3, w1, b1, nullptr, F1, ROWS, 256, FFNN);
    // 12) x3 = x2 + f1 @ w2.T + b2
    gemm_proj<false, true><<<dim3(13, 4), 256, 0, stream>>>(
        F1, w2, b2, X2, X3, ROWS, FFNN, 256);
    // 13) out = ln(x3, n4)
    ln_kernel<<<ROWS, 256, 0, stream>>>(X3, n4_g, n4_b, out);
}